// Round 1
// baseline (5334.145 us; speedup 1.0000x reference)
//
#include <hip/hip_runtime.h>

#define NLEV 16
#define TSIZE (1u << 19)
#define TMASK (TSIZE - 1u)
#define WIDTH 64
#define P1 2654435761u
#define P2 805459861u
#define P3 3674653429u

__device__ __forceinline__ void enc3_level(const float2* __restrict__ tab, float res,
                                           float x, float y, float z,
                                           float& f0, float& f1) {
  float px = x * res, py = y * res, pz = z * res;
  float fx = floorf(px), fy = floorf(py), fz = floorf(pz);
  float wx = px - fx, wy = py - fy, wz = pz - fz;
  unsigned cx = (unsigned)fx, cy = (unsigned)fy, cz = (unsigned)fz;
  unsigned hx[2] = {cx, cx + 1u};
  unsigned hy[2] = {cy * P1, cy * P1 + P1};
  unsigned hz[2] = {cz * P2, cz * P2 + P2};
  float vx[2] = {1.f - wx, wx};
  float vy[2] = {1.f - wy, wy};
  float vz[2] = {1.f - wz, wz};
  f0 = 0.f; f1 = 0.f;
#pragma unroll
  for (int j = 0; j < 8; ++j) {
    const int dx = (j >> 2) & 1, dy = (j >> 1) & 1, dz = j & 1;
    unsigned h = (hx[dx] ^ hy[dy] ^ hz[dz]) & TMASK;
    float2 g = tab[h];
    float w = vx[dx] * vy[dy] * vz[dz];
    f0 = fmaf(w, g.x, f0);
    f1 = fmaf(w, g.y, f1);
  }
}

__device__ __forceinline__ void enc4_level(const float2* __restrict__ tab, float res,
                                           float x, float y, float z, float u,
                                           float& f0, float& f1) {
  float px = x * res, py = y * res, pz = z * res, pu = u * res;
  float fx = floorf(px), fy = floorf(py), fz = floorf(pz), fu = floorf(pu);
  float wx = px - fx, wy = py - fy, wz = pz - fz, wu = pu - fu;
  unsigned cx = (unsigned)fx, cy = (unsigned)fy, cz = (unsigned)fz, cu = (unsigned)fu;
  unsigned hx[2] = {cx, cx + 1u};
  unsigned hy[2] = {cy * P1, cy * P1 + P1};
  unsigned hz[2] = {cz * P2, cz * P2 + P2};
  unsigned hu[2] = {cu * P3, cu * P3 + P3};
  float vx[2] = {1.f - wx, wx};
  float vy[2] = {1.f - wy, wy};
  float vz[2] = {1.f - wz, wz};
  float vu[2] = {1.f - wu, wu};
  f0 = 0.f; f1 = 0.f;
#pragma unroll
  for (int j = 0; j < 16; ++j) {
    const int dx = (j >> 3) & 1, dy = (j >> 2) & 1, dz = (j >> 1) & 1, du = j & 1;
    unsigned h = (hx[dx] ^ hy[dy] ^ hz[dz] ^ hu[du]) & TMASK;
    float2 g = tab[h];
    float w = ((vx[dx] * vy[dy]) * vz[dz]) * vu[du];
    f0 = fmaf(w, g.x, f0);
    f1 = fmaf(w, g.y, f1);
  }
}

__global__ __launch_bounds__(256, 2)
void hashgrid_mlp(const float* __restrict__ pos,
                  const float* __restrict__ nrm,
                  const float* __restrict__ pose,
                  const float2* __restrict__ tpos,
                  const float2* __restrict__ tnrm,
                  const float2* __restrict__ tpose,
                  const float* __restrict__ W1,
                  const float* __restrict__ W2,
                  const float* __restrict__ W3,
                  float* __restrict__ out,
                  int n) {
  __shared__ float sW1[96 * WIDTH];
  __shared__ float sW2[WIDTH * WIDTH];
  __shared__ float sW3[WIDTH * 9];
  for (int i = threadIdx.x; i < 96 * WIDTH; i += 256) sW1[i] = W1[i];
  for (int i = threadIdx.x; i < WIDTH * WIDTH; i += 256) sW2[i] = W2[i];
  for (int i = threadIdx.x; i < WIDTH * 9; i += 256) sW3[i] = W3[i];
  __syncthreads();

  // floor(16 * 1.5^l), exactly representable in f32
  static constexpr float kRes[NLEV] = {16.f, 24.f, 36.f, 54.f, 81.f, 121.f, 182.f, 273.f,
                                       410.f, 615.f, 922.f, 1383.f, 2075.f, 3113.f, 4670.f, 7006.f};

  const int stride = gridDim.x * 256;
  for (int i = blockIdx.x * 256 + threadIdx.x; i < n; i += stride) {
    float h1[WIDTH];
#pragma unroll
    for (int k = 0; k < WIDTH; ++k) h1[k] = 0.f;

    // ---- encoder 0: face_centers (W1 rows 0..31)
    {
      const float x = pos[3 * i + 0], y = pos[3 * i + 1], z = pos[3 * i + 2];
#pragma unroll
      for (int l = 0; l < NLEV; ++l) {
        float f0, f1;
        enc3_level(tpos + (size_t)l * TSIZE, kRes[l], x, y, z, f0, f1);
        const float* w = &sW1[(2 * l) * WIDTH];
#pragma unroll
        for (int k = 0; k < WIDTH; ++k)
          h1[k] = fmaf(f1, w[WIDTH + k], fmaf(f0, w[k], h1[k]));
      }
    }
    // ---- encoder 1: face_normals (W1 rows 32..63)
    {
      const float x = nrm[3 * i + 0], y = nrm[3 * i + 1], z = nrm[3 * i + 2];
#pragma unroll
      for (int l = 0; l < NLEV; ++l) {
        float f0, f1;
        enc3_level(tnrm + (size_t)l * TSIZE, kRes[l], x, y, z, f0, f1);
        const float* w = &sW1[(32 + 2 * l) * WIDTH];
#pragma unroll
        for (int k = 0; k < WIDTH; ++k)
          h1[k] = fmaf(f1, w[WIDTH + k], fmaf(f0, w[k], h1[k]));
      }
    }
    // ---- encoder 2: pose_extended, 4-D (W1 rows 64..95)
    {
      const float x = pose[4 * i + 0], y = pose[4 * i + 1], z = pose[4 * i + 2], u = pose[4 * i + 3];
#pragma unroll
      for (int l = 0; l < NLEV; ++l) {
        float f0, f1;
        enc4_level(tpose + (size_t)l * TSIZE, kRes[l], x, y, z, u, f0, f1);
        const float* w = &sW1[(64 + 2 * l) * WIDTH];
#pragma unroll
        for (int k = 0; k < WIDTH; ++k)
          h1[k] = fmaf(f1, w[WIDTH + k], fmaf(f0, w[k], h1[k]));
      }
    }

    // ---- layer 2: h2 = relu(h1) @ W2
    float h2[WIDTH];
#pragma unroll
    for (int k = 0; k < WIDTH; ++k) h2[k] = 0.f;
#pragma unroll
    for (int j = 0; j < WIDTH; ++j) {
      const float a = fmaxf(h1[j], 0.f);
      const float* w = &sW2[j * WIDTH];
#pragma unroll
      for (int k = 0; k < WIDTH; ++k) h2[k] = fmaf(a, w[k], h2[k]);
    }

    // ---- layer 3: out = relu(h2) @ W3
    float o[9];
#pragma unroll
    for (int k = 0; k < 9; ++k) o[k] = 0.f;
#pragma unroll
    for (int j = 0; j < WIDTH; ++j) {
      const float a = fmaxf(h2[j], 0.f);
      const float* w = &sW3[j * 9];
#pragma unroll
      for (int k = 0; k < 9; ++k) o[k] = fmaf(a, w[k], o[k]);
    }
#pragma unroll
    for (int k = 0; k < 9; ++k) out[(size_t)i * 9 + k] = o[k];
  }
}

extern "C" void kernel_launch(void* const* d_in, const int* in_sizes, int n_in,
                              void* d_out, int out_size, void* d_ws, size_t ws_size,
                              hipStream_t stream) {
  const float* pos  = (const float*)d_in[0];
  const float* nrm  = (const float*)d_in[1];
  const float* pose = (const float*)d_in[2];
  const float2* tpos  = (const float2*)d_in[3];
  const float2* tnrm  = (const float2*)d_in[4];
  const float2* tpose = (const float2*)d_in[5];
  const float* W1 = (const float*)d_in[6];
  const float* W2 = (const float*)d_in[7];
  const float* W3 = (const float*)d_in[8];
  float* out = (float*)d_out;
  const int n = in_sizes[0] / 3;

  const int threads = 256;
  const int blocks = 512;  // 2 blocks/CU persistent, grid-stride
  hipLaunchKernelGGL(hashgrid_mlp, dim3(blocks), dim3(threads), 0, stream,
                     pos, nrm, pose, tpos, tnrm, tpose, W1, W2, W3, out, n);
}

// Round 3
// 2735.118 us; speedup vs baseline: 1.9502x; 1.9502x over previous
//
#include <hip/hip_runtime.h>
#include <hip/hip_fp16.h>

#define NLEV 16
#define TSIZE (1u << 19)
#define TMASK (TSIZE - 1u)
#define WIDTH 64
#define P1 2654435761u
#define P2 805459861u
#define P3 3674653429u

// floor(16 * 1.5^l) — exactly representable in f32
__constant__ float kResC[NLEV] = {16.f, 24.f, 36.f, 54.f, 81.f, 121.f, 182.f, 273.f,
                                  410.f, 615.f, 922.f, 1383.f, 2075.f, 3113.f, 4670.f, 7006.f};

// ---- non-temporal load/store helpers (keep streaming data out of L2's way)
__device__ __forceinline__ void st_nt(float* p, float v) { __builtin_nontemporal_store(v, p); }
__device__ __forceinline__ void st_nt(__half* p, float v) {
  __builtin_nontemporal_store(__half_as_ushort(__float2half(v)), (unsigned short*)p);
}
__device__ __forceinline__ float ld_nt_f(const float* p) { return __builtin_nontemporal_load(p); }
__device__ __forceinline__ float ld_enc(const float* p) { return __builtin_nontemporal_load(p); }
__device__ __forceinline__ float ld_enc(const __half* p) {
  return __half2float(__ushort_as_half(__builtin_nontemporal_load((const unsigned short*)p)));
}

// ============================================================================
// Encode passes: one (table, level) slice per pass so the 4 MB slice stays
// L2-resident per XCD. Pass ordering comes from blockIdx dispatch order.
// enc layout: [96][N] (row = table*32 + level*2 + feature) so MLP reads coalesce.
// ============================================================================

template <typename ST>
__global__ __launch_bounds__(256)
void encode3(const float* __restrict__ coords,   // [N,3]
             const float2* __restrict__ table,   // [16][TSIZE] float2 base
             ST* __restrict__ enc,               // [96][N]
             int N, int BPP, int rowBase) {
  const unsigned blk = blockIdx.x;
  const unsigned lvl = blk / (unsigned)BPP;
  const unsigned b = blk - lvl * (unsigned)BPP;
  const int i = (int)(b * 256u + threadIdx.x);
  if (i >= N) return;
  const float res = kResC[lvl];
  const float2* __restrict__ tab = table + (size_t)lvl * TSIZE;

  const float px = ld_nt_f(&coords[(size_t)i * 3 + 0]) * res;
  const float py = ld_nt_f(&coords[(size_t)i * 3 + 1]) * res;
  const float pz = ld_nt_f(&coords[(size_t)i * 3 + 2]) * res;
  const float fx = floorf(px), fy = floorf(py), fz = floorf(pz);
  const float wx = px - fx, wy = py - fy, wz = pz - fz;
  const unsigned cx = (unsigned)fx, cy = (unsigned)fy, cz = (unsigned)fz;
  unsigned hx[2] = {cx, cx + 1u};
  unsigned hy[2] = {cy * P1, cy * P1 + P1};
  unsigned hz[2] = {cz * P2, cz * P2 + P2};
  float vx[2] = {1.f - wx, wx};
  float vy[2] = {1.f - wy, wy};
  float vz[2] = {1.f - wz, wz};
  float f0 = 0.f, f1 = 0.f;
#pragma unroll
  for (int j = 0; j < 8; ++j) {
    const int dx = (j >> 2) & 1, dy = (j >> 1) & 1, dz = j & 1;
    const unsigned h = (hx[dx] ^ hy[dy] ^ hz[dz]) & TMASK;
    const float2 g = tab[h];
    const float w = vx[dx] * vy[dy] * vz[dz];
    f0 = fmaf(w, g.x, f0);
    f1 = fmaf(w, g.y, f1);
  }
  const int row = rowBase + 2 * (int)lvl;
  st_nt(&enc[(size_t)row * N + i], f0);
  st_nt(&enc[(size_t)(row + 1) * N + i], f1);
}

template <typename ST>
__global__ __launch_bounds__(256)
void encode4(const float* __restrict__ coords,   // [N,4]
             const float2* __restrict__ table,
             ST* __restrict__ enc,
             int N, int BPP, int rowBase) {
  const unsigned blk = blockIdx.x;
  const unsigned lvl = blk / (unsigned)BPP;
  const unsigned b = blk - lvl * (unsigned)BPP;
  const int i = (int)(b * 256u + threadIdx.x);
  if (i >= N) return;
  const float res = kResC[lvl];
  const float2* __restrict__ tab = table + (size_t)lvl * TSIZE;

  const float px = ld_nt_f(&coords[(size_t)i * 4 + 0]) * res;
  const float py = ld_nt_f(&coords[(size_t)i * 4 + 1]) * res;
  const float pz = ld_nt_f(&coords[(size_t)i * 4 + 2]) * res;
  const float pu = ld_nt_f(&coords[(size_t)i * 4 + 3]) * res;
  const float fx = floorf(px), fy = floorf(py), fz = floorf(pz), fu = floorf(pu);
  const float wx = px - fx, wy = py - fy, wz = pz - fz, wu = pu - fu;
  const unsigned cx = (unsigned)fx, cy = (unsigned)fy, cz = (unsigned)fz, cu = (unsigned)fu;
  unsigned hx[2] = {cx, cx + 1u};
  unsigned hy[2] = {cy * P1, cy * P1 + P1};
  unsigned hz[2] = {cz * P2, cz * P2 + P2};
  unsigned hu[2] = {cu * P3, cu * P3 + P3};
  float vx[2] = {1.f - wx, wx};
  float vy[2] = {1.f - wy, wy};
  float vz[2] = {1.f - wz, wz};
  float vu[2] = {1.f - wu, wu};
  float f0 = 0.f, f1 = 0.f;
#pragma unroll
  for (int j = 0; j < 16; ++j) {
    const int dx = (j >> 3) & 1, dy = (j >> 2) & 1, dz = (j >> 1) & 1, du = j & 1;
    const unsigned h = (hx[dx] ^ hy[dy] ^ hz[dz] ^ hu[du]) & TMASK;
    const float2 g = tab[h];
    const float w = ((vx[dx] * vy[dy]) * vz[dz]) * vu[du];
    f0 = fmaf(w, g.x, f0);
    f1 = fmaf(w, g.y, f1);
  }
  const int row = rowBase + 2 * (int)lvl;
  st_nt(&enc[(size_t)row * N + i], f0);
  st_nt(&enc[(size_t)(row + 1) * N + i], f1);
}

// ============================================================================
// MLP pass: enc[96][N] -> out[N][9]. Weights staged in LDS (broadcast reads).
// ============================================================================
template <typename ST>
__global__ __launch_bounds__(256)
void mlp_pass(const ST* __restrict__ enc,
              const float* __restrict__ W1, const float* __restrict__ W2,
              const float* __restrict__ W3, float* __restrict__ out, int N) {
  __shared__ float sW1[96 * WIDTH];
  __shared__ float sW2[WIDTH * WIDTH];
  __shared__ float sW3[WIDTH * 9];
  for (int k = threadIdx.x; k < 96 * WIDTH; k += 256) sW1[k] = W1[k];
  for (int k = threadIdx.x; k < WIDTH * WIDTH; k += 256) sW2[k] = W2[k];
  for (int k = threadIdx.x; k < WIDTH * 9; k += 256) sW3[k] = W3[k];
  __syncthreads();

  const int i = blockIdx.x * 256 + threadIdx.x;
  if (i >= N) return;

  float h1[WIDTH];
#pragma unroll
  for (int j = 0; j < WIDTH; ++j) h1[j] = 0.f;
#pragma unroll 6
  for (int k = 0; k < 96; ++k) {
    const float a = ld_enc(&enc[(size_t)k * N + i]);
    const float* w = &sW1[k * WIDTH];
#pragma unroll
    for (int j = 0; j < WIDTH; ++j) h1[j] = fmaf(a, w[j], h1[j]);
  }

  float h2[WIDTH];
#pragma unroll
  for (int j = 0; j < WIDTH; ++j) h2[j] = 0.f;
#pragma unroll
  for (int j = 0; j < WIDTH; ++j) {   // full unroll: h1[j]/h2[k] must be reg-indexed
    const float a = fmaxf(h1[j], 0.f);
    const float* w = &sW2[j * WIDTH];
#pragma unroll
    for (int k = 0; k < WIDTH; ++k) h2[k] = fmaf(a, w[k], h2[k]);
  }

  float o[9];
#pragma unroll
  for (int k = 0; k < 9; ++k) o[k] = 0.f;
#pragma unroll
  for (int j = 0; j < WIDTH; ++j) {
    const float a = fmaxf(h2[j], 0.f);
    const float* w = &sW3[j * 9];
#pragma unroll
    for (int k = 0; k < 9; ++k) o[k] = fmaf(a, w[k], o[k]);
  }
#pragma unroll
  for (int k = 0; k < 9; ++k) st_nt(&out[(size_t)i * 9 + k], o[k]);
}

// ============================================================================
// Fallback: round-0 fused kernel (known-correct) if workspace is too small.
// ============================================================================
__device__ __forceinline__ void enc3_level(const float2* __restrict__ tab, float res,
                                           float x, float y, float z, float& f0, float& f1) {
  float px = x * res, py = y * res, pz = z * res;
  float fx = floorf(px), fy = floorf(py), fz = floorf(pz);
  float wx = px - fx, wy = py - fy, wz = pz - fz;
  unsigned cx = (unsigned)fx, cy = (unsigned)fy, cz = (unsigned)fz;
  unsigned hx[2] = {cx, cx + 1u};
  unsigned hy[2] = {cy * P1, cy * P1 + P1};
  unsigned hz[2] = {cz * P2, cz * P2 + P2};
  float vx[2] = {1.f - wx, wx}, vy[2] = {1.f - wy, wy}, vz[2] = {1.f - wz, wz};
  f0 = 0.f; f1 = 0.f;
#pragma unroll
  for (int j = 0; j < 8; ++j) {
    const int dx = (j >> 2) & 1, dy = (j >> 1) & 1, dz = j & 1;
    unsigned h = (hx[dx] ^ hy[dy] ^ hz[dz]) & TMASK;
    float2 g = tab[h];
    float w = vx[dx] * vy[dy] * vz[dz];
    f0 = fmaf(w, g.x, f0); f1 = fmaf(w, g.y, f1);
  }
}
__device__ __forceinline__ void enc4_level(const float2* __restrict__ tab, float res,
                                           float x, float y, float z, float u, float& f0, float& f1) {
  float px = x * res, py = y * res, pz = z * res, pu = u * res;
  float fx = floorf(px), fy = floorf(py), fz = floorf(pz), fu = floorf(pu);
  float wx = px - fx, wy = py - fy, wz = pz - fz, wu = pu - fu;
  unsigned cx = (unsigned)fx, cy = (unsigned)fy, cz = (unsigned)fz, cu = (unsigned)fu;
  unsigned hx[2] = {cx, cx + 1u};
  unsigned hy[2] = {cy * P1, cy * P1 + P1};
  unsigned hz[2] = {cz * P2, cz * P2 + P2};
  unsigned hu[2] = {cu * P3, cu * P3 + P3};
  float vx[2] = {1.f - wx, wx}, vy[2] = {1.f - wy, wy}, vz[2] = {1.f - wz, wz}, vu[2] = {1.f - wu, wu};
  f0 = 0.f; f1 = 0.f;
#pragma unroll
  for (int j = 0; j < 16; ++j) {
    const int dx = (j >> 3) & 1, dy = (j >> 2) & 1, dz = (j >> 1) & 1, du = j & 1;
    unsigned h = (hx[dx] ^ hy[dy] ^ hz[dz] ^ hu[du]) & TMASK;
    float2 g = tab[h];
    float w = ((vx[dx] * vy[dy]) * vz[dz]) * vu[du];
    f0 = fmaf(w, g.x, f0); f1 = fmaf(w, g.y, f1);
  }
}

__global__ __launch_bounds__(256, 2)
void hashgrid_mlp_fused(const float* __restrict__ pos, const float* __restrict__ nrm,
                        const float* __restrict__ pose, const float2* __restrict__ tpos,
                        const float2* __restrict__ tnrm, const float2* __restrict__ tpose,
                        const float* __restrict__ W1, const float* __restrict__ W2,
                        const float* __restrict__ W3, float* __restrict__ out, int n) {
  __shared__ float sW1[96 * WIDTH];
  __shared__ float sW2[WIDTH * WIDTH];
  __shared__ float sW3[WIDTH * 9];
  for (int i = threadIdx.x; i < 96 * WIDTH; i += 256) sW1[i] = W1[i];
  for (int i = threadIdx.x; i < WIDTH * WIDTH; i += 256) sW2[i] = W2[i];
  for (int i = threadIdx.x; i < WIDTH * 9; i += 256) sW3[i] = W3[i];
  __syncthreads();
  const int stride = gridDim.x * 256;
  for (int i = blockIdx.x * 256 + threadIdx.x; i < n; i += stride) {
    float h1[WIDTH];
#pragma unroll
    for (int k = 0; k < WIDTH; ++k) h1[k] = 0.f;
    {
      const float x = pos[3 * i], y = pos[3 * i + 1], z = pos[3 * i + 2];
#pragma unroll
      for (int l = 0; l < NLEV; ++l) {
        float f0, f1;
        enc3_level(tpos + (size_t)l * TSIZE, kResC[l], x, y, z, f0, f1);
        const float* w = &sW1[(2 * l) * WIDTH];
#pragma unroll
        for (int k = 0; k < WIDTH; ++k) h1[k] = fmaf(f1, w[WIDTH + k], fmaf(f0, w[k], h1[k]));
      }
    }
    {
      const float x = nrm[3 * i], y = nrm[3 * i + 1], z = nrm[3 * i + 2];
#pragma unroll
      for (int l = 0; l < NLEV; ++l) {
        float f0, f1;
        enc3_level(tnrm + (size_t)l * TSIZE, kResC[l], x, y, z, f0, f1);
        const float* w = &sW1[(32 + 2 * l) * WIDTH];
#pragma unroll
        for (int k = 0; k < WIDTH; ++k) h1[k] = fmaf(f1, w[WIDTH + k], fmaf(f0, w[k], h1[k]));
      }
    }
    {
      const float x = pose[4 * i], y = pose[4 * i + 1], z = pose[4 * i + 2], u = pose[4 * i + 3];
#pragma unroll
      for (int l = 0; l < NLEV; ++l) {
        float f0, f1;
        enc4_level(tpose + (size_t)l * TSIZE, kResC[l], x, y, z, u, f0, f1);
        const float* w = &sW1[(64 + 2 * l) * WIDTH];
#pragma unroll
        for (int k = 0; k < WIDTH; ++k) h1[k] = fmaf(f1, w[WIDTH + k], fmaf(f0, w[k], h1[k]));
      }
    }
    float h2[WIDTH];
#pragma unroll
    for (int k = 0; k < WIDTH; ++k) h2[k] = 0.f;
#pragma unroll
    for (int j = 0; j < WIDTH; ++j) {
      const float a = fmaxf(h1[j], 0.f);
      const float* w = &sW2[j * WIDTH];
#pragma unroll
      for (int k = 0; k < WIDTH; ++k) h2[k] = fmaf(a, w[k], h2[k]);
    }
    float o[9];
#pragma unroll
    for (int k = 0; k < 9; ++k) o[k] = 0.f;
#pragma unroll
    for (int j = 0; j < WIDTH; ++j) {
      const float a = fmaxf(h2[j], 0.f);
      const float* w = &sW3[j * 9];
#pragma unroll
      for (int k = 0; k < 9; ++k) o[k] = fmaf(a, w[k], o[k]);
    }
#pragma unroll
    for (int k = 0; k < 9; ++k) out[(size_t)i * 9 + k] = o[k];
  }
}

// ============================================================================
extern "C" void kernel_launch(void* const* d_in, const int* in_sizes, int n_in,
                              void* d_out, int out_size, void* d_ws, size_t ws_size,
                              hipStream_t stream) {
  const float* pos  = (const float*)d_in[0];
  const float* nrm  = (const float*)d_in[1];
  const float* pose = (const float*)d_in[2];
  const float2* tpos  = (const float2*)d_in[3];
  const float2* tnrm  = (const float2*)d_in[4];
  const float2* tpose = (const float2*)d_in[5];
  const float* W1 = (const float*)d_in[6];
  const float* W2 = (const float*)d_in[7];
  const float* W3 = (const float*)d_in[8];
  float* out = (float*)d_out;
  const int n = in_sizes[0] / 3;

  const size_t needF = (size_t)96 * n * sizeof(float);
  const size_t needH = (size_t)96 * n * sizeof(__half);
  const int BPP = (n + 255) / 256;          // blocks per (table,level) pass
  const dim3 encGrid(16 * BPP), blk(256), mlpGrid(BPP);

  if (ws_size >= needF) {
    float* enc = (float*)d_ws;
    hipLaunchKernelGGL(encode3<float>, encGrid, blk, 0, stream, pos,  tpos,  enc, n, BPP, 0);
    hipLaunchKernelGGL(encode3<float>, encGrid, blk, 0, stream, nrm,  tnrm,  enc, n, BPP, 32);
    hipLaunchKernelGGL(encode4<float>, encGrid, blk, 0, stream, pose, tpose, enc, n, BPP, 64);
    hipLaunchKernelGGL(mlp_pass<float>, mlpGrid, blk, 0, stream, enc, W1, W2, W3, out, n);
  } else if (ws_size >= needH) {
    __half* enc = (__half*)d_ws;
    hipLaunchKernelGGL(encode3<__half>, encGrid, blk, 0, stream, pos,  tpos,  enc, n, BPP, 0);
    hipLaunchKernelGGL(encode3<__half>, encGrid, blk, 0, stream, nrm,  tnrm,  enc, n, BPP, 32);
    hipLaunchKernelGGL(encode4<__half>, encGrid, blk, 0, stream, pose, tpose, enc, n, BPP, 64);
    hipLaunchKernelGGL(mlp_pass<__half>, mlpGrid, blk, 0, stream, enc, W1, W2, W3, out, n);
  } else {
    hipLaunchKernelGGL(hashgrid_mlp_fused, dim3(512), blk, 0, stream,
                       pos, nrm, pose, tpos, tnrm, tpose, W1, W2, W3, out, n);
  }
}

// Round 4
// 2728.221 us; speedup vs baseline: 1.9552x; 1.0025x over previous
//
#include <hip/hip_runtime.h>
#include <hip/hip_fp16.h>

#define NLEV 16
#define TSIZE (1u << 19)
#define TMASK (TSIZE - 1u)
#define WIDTH 64
#define P1 2654435761u
#define P2 805459861u
#define P3 3674653429u

// floor(16 * 1.5^l) — exactly representable in f32
__constant__ float kResC[NLEV] = {16.f, 24.f, 36.f, 54.f, 81.f, 121.f, 182.f, 273.f,
                                  410.f, 615.f, 922.f, 1383.f, 2075.f, 3113.f, 4670.f, 7006.f};

// ---- non-temporal load/store helpers (keep streaming data out of the table's L2)
__device__ __forceinline__ void st_nt(float* p, float v) { __builtin_nontemporal_store(v, p); }
__device__ __forceinline__ void st_nt(__half* p, float v) {
  __builtin_nontemporal_store(__half_as_ushort(__float2half(v)), (unsigned short*)p);
}
__device__ __forceinline__ float ld_nt_f(const float* p) { return __builtin_nontemporal_load(p); }
__device__ __forceinline__ float ld_enc(const float* p) { return __builtin_nontemporal_load(p); }
__device__ __forceinline__ float ld_enc(const __half* p) {
  return __half2float(__ushort_as_half(__builtin_nontemporal_load((const unsigned short*)p)));
}

// ============================================================================
// Encode passes: one (table, level) 4 MB slice per pass (L2-resident per XCD);
// pass order from blockIdx. ILP restructure: compute ALL hash indices, issue
// ALL gathers into independent regs, then reduce — keeps 8/16 loads in flight
// per wave to hide L2/L3 latency (round-3 VGPR=28 showed serialized loads).
// enc layout: [96][N] so the MLP pass reads coalesce.
// ============================================================================

template <typename ST>
__global__ __launch_bounds__(256)
void encode3(const float* __restrict__ coords,   // [N,3]
             const float2* __restrict__ table,   // [16][TSIZE] float2
             ST* __restrict__ enc,               // [96][N]
             int N, int BPP, int rowBase) {
  const unsigned blk = blockIdx.x;
  const unsigned lvl = blk / (unsigned)BPP;
  const unsigned b = blk - lvl * (unsigned)BPP;
  const int i = (int)(b * 256u + threadIdx.x);
  if (i >= N) return;
  const float res = kResC[lvl];
  const float2* __restrict__ tab = table + (size_t)lvl * TSIZE;

  const float px = ld_nt_f(&coords[(size_t)i * 3 + 0]) * res;
  const float py = ld_nt_f(&coords[(size_t)i * 3 + 1]) * res;
  const float pz = ld_nt_f(&coords[(size_t)i * 3 + 2]) * res;
  const float fx = floorf(px), fy = floorf(py), fz = floorf(pz);
  const float wx = px - fx, wy = py - fy, wz = pz - fz;
  const unsigned cx = (unsigned)fx, cy = (unsigned)fy, cz = (unsigned)fz;
  const unsigned hx0 = cx, hx1 = cx + 1u;
  const unsigned hy0 = cy * P1, hy1 = hy0 + P1;
  const unsigned hz0 = cz * P2, hz1 = hz0 + P2;

  // all 8 indices first
  unsigned idx[8];
  idx[0] = (hx0 ^ hy0 ^ hz0) & TMASK;
  idx[1] = (hx0 ^ hy0 ^ hz1) & TMASK;
  idx[2] = (hx0 ^ hy1 ^ hz0) & TMASK;
  idx[3] = (hx0 ^ hy1 ^ hz1) & TMASK;
  idx[4] = (hx1 ^ hy0 ^ hz0) & TMASK;
  idx[5] = (hx1 ^ hy0 ^ hz1) & TMASK;
  idx[6] = (hx1 ^ hy1 ^ hz0) & TMASK;
  idx[7] = (hx1 ^ hy1 ^ hz1) & TMASK;

  // all 8 gathers in flight
  float2 g[8];
#pragma unroll
  for (int j = 0; j < 8; ++j) g[j] = tab[idx[j]];

  const float vx[2] = {1.f - wx, wx};
  const float vy[2] = {1.f - wy, wy};
  const float vz[2] = {1.f - wz, wz};
  float f0 = 0.f, f1 = 0.f;
#pragma unroll
  for (int j = 0; j < 8; ++j) {
    const int dx = (j >> 2) & 1, dy = (j >> 1) & 1, dz = j & 1;
    const float w = vx[dx] * vy[dy] * vz[dz];
    f0 = fmaf(w, g[j].x, f0);
    f1 = fmaf(w, g[j].y, f1);
  }
  const int row = rowBase + 2 * (int)lvl;
  st_nt(&enc[(size_t)row * N + i], f0);
  st_nt(&enc[(size_t)(row + 1) * N + i], f1);
}

template <typename ST>
__global__ __launch_bounds__(256)
void encode4(const float* __restrict__ coords,   // [N,4]
             const float2* __restrict__ table,
             ST* __restrict__ enc,
             int N, int BPP, int rowBase) {
  const unsigned blk = blockIdx.x;
  const unsigned lvl = blk / (unsigned)BPP;
  const unsigned b = blk - lvl * (unsigned)BPP;
  const int i = (int)(b * 256u + threadIdx.x);
  if (i >= N) return;
  const float res = kResC[lvl];
  const float2* __restrict__ tab = table + (size_t)lvl * TSIZE;

  const float px = ld_nt_f(&coords[(size_t)i * 4 + 0]) * res;
  const float py = ld_nt_f(&coords[(size_t)i * 4 + 1]) * res;
  const float pz = ld_nt_f(&coords[(size_t)i * 4 + 2]) * res;
  const float pu = ld_nt_f(&coords[(size_t)i * 4 + 3]) * res;
  const float fx = floorf(px), fy = floorf(py), fz = floorf(pz), fu = floorf(pu);
  const float wx = px - fx, wy = py - fy, wz = pz - fz, wu = pu - fu;
  const unsigned cx = (unsigned)fx, cy = (unsigned)fy, cz = (unsigned)fz, cu = (unsigned)fu;
  const unsigned hx0 = cx, hx1 = cx + 1u;
  const unsigned hy0 = cy * P1, hy1 = hy0 + P1;
  const unsigned hz0 = cz * P2, hz1 = hz0 + P2;
  const unsigned hu0 = cu * P3, hu1 = hu0 + P3;

  unsigned idx[16];
#pragma unroll
  for (int j = 0; j < 16; ++j) {
    const unsigned a = (j & 8) ? hx1 : hx0;
    const unsigned bq = (j & 4) ? hy1 : hy0;
    const unsigned c = (j & 2) ? hz1 : hz0;
    const unsigned d = (j & 1) ? hu1 : hu0;
    idx[j] = (a ^ bq ^ c ^ d) & TMASK;
  }

  // all 16 gathers in flight
  float2 g[16];
#pragma unroll
  for (int j = 0; j < 16; ++j) g[j] = tab[idx[j]];

  const float vx[2] = {1.f - wx, wx};
  const float vy[2] = {1.f - wy, wy};
  const float vz[2] = {1.f - wz, wz};
  const float vu[2] = {1.f - wu, wu};
  float f0 = 0.f, f1 = 0.f;
#pragma unroll
  for (int j = 0; j < 16; ++j) {
    const int dx = (j >> 3) & 1, dy = (j >> 2) & 1, dz = (j >> 1) & 1, du = j & 1;
    const float w = ((vx[dx] * vy[dy]) * vz[dz]) * vu[du];
    f0 = fmaf(w, g[j].x, f0);
    f1 = fmaf(w, g[j].y, f1);
  }
  const int row = rowBase + 2 * (int)lvl;
  st_nt(&enc[(size_t)row * N + i], f0);
  st_nt(&enc[(size_t)(row + 1) * N + i], f1);
}

// ============================================================================
// MLP pass: enc[96][N] -> out[N][9]. Weights in LDS (broadcast reads);
// activation loads batched 8-wide to overlap with FMA work.
// ============================================================================
template <typename ST>
__global__ __launch_bounds__(256)
void mlp_pass(const ST* __restrict__ enc,
              const float* __restrict__ W1, const float* __restrict__ W2,
              const float* __restrict__ W3, float* __restrict__ out, int N) {
  __shared__ float sW1[96 * WIDTH];
  __shared__ float sW2[WIDTH * WIDTH];
  __shared__ float sW3[WIDTH * 9];
  for (int k = threadIdx.x; k < 96 * WIDTH; k += 256) sW1[k] = W1[k];
  for (int k = threadIdx.x; k < WIDTH * WIDTH; k += 256) sW2[k] = W2[k];
  for (int k = threadIdx.x; k < WIDTH * 9; k += 256) sW3[k] = W3[k];
  __syncthreads();

  const int i = blockIdx.x * 256 + threadIdx.x;
  if (i >= N) return;

  float h1[WIDTH];
#pragma unroll
  for (int j = 0; j < WIDTH; ++j) h1[j] = 0.f;
#pragma unroll 1
  for (int kb = 0; kb < 96; kb += 8) {
    float a8[8];
#pragma unroll
    for (int t = 0; t < 8; ++t) a8[t] = ld_enc(&enc[(size_t)(kb + t) * N + i]);
#pragma unroll
    for (int t = 0; t < 8; ++t) {
      const float* w = &sW1[(kb + t) * WIDTH];
#pragma unroll
      for (int j = 0; j < WIDTH; ++j) h1[j] = fmaf(a8[t], w[j], h1[j]);
    }
  }

  float h2[WIDTH];
#pragma unroll
  for (int j = 0; j < WIDTH; ++j) h2[j] = 0.f;
#pragma unroll
  for (int j = 0; j < WIDTH; ++j) {   // full unroll: h1/h2 must stay reg-indexed
    const float a = fmaxf(h1[j], 0.f);
    const float* w = &sW2[j * WIDTH];
#pragma unroll
    for (int k = 0; k < WIDTH; ++k) h2[k] = fmaf(a, w[k], h2[k]);
  }

  float o[9];
#pragma unroll
  for (int k = 0; k < 9; ++k) o[k] = 0.f;
#pragma unroll
  for (int j = 0; j < WIDTH; ++j) {
    const float a = fmaxf(h2[j], 0.f);
    const float* w = &sW3[j * 9];
#pragma unroll
    for (int k = 0; k < 9; ++k) o[k] = fmaf(a, w[k], o[k]);
  }
#pragma unroll
  for (int k = 0; k < 9; ++k) st_nt(&out[(size_t)i * 9 + k], o[k]);
}

// ============================================================================
// Fallback: fused kernel (known-correct) if workspace is too small.
// ============================================================================
__device__ __forceinline__ void enc3_level(const float2* __restrict__ tab, float res,
                                           float x, float y, float z, float& f0, float& f1) {
  float px = x * res, py = y * res, pz = z * res;
  float fx = floorf(px), fy = floorf(py), fz = floorf(pz);
  float wx = px - fx, wy = py - fy, wz = pz - fz;
  unsigned cx = (unsigned)fx, cy = (unsigned)fy, cz = (unsigned)fz;
  unsigned hx[2] = {cx, cx + 1u};
  unsigned hy[2] = {cy * P1, cy * P1 + P1};
  unsigned hz[2] = {cz * P2, cz * P2 + P2};
  float vx[2] = {1.f - wx, wx}, vy[2] = {1.f - wy, wy}, vz[2] = {1.f - wz, wz};
  f0 = 0.f; f1 = 0.f;
#pragma unroll
  for (int j = 0; j < 8; ++j) {
    const int dx = (j >> 2) & 1, dy = (j >> 1) & 1, dz = j & 1;
    unsigned h = (hx[dx] ^ hy[dy] ^ hz[dz]) & TMASK;
    float2 g = tab[h];
    float w = vx[dx] * vy[dy] * vz[dz];
    f0 = fmaf(w, g.x, f0); f1 = fmaf(w, g.y, f1);
  }
}
__device__ __forceinline__ void enc4_level(const float2* __restrict__ tab, float res,
                                           float x, float y, float z, float u, float& f0, float& f1) {
  float px = x * res, py = y * res, pz = z * res, pu = u * res;
  float fx = floorf(px), fy = floorf(py), fz = floorf(pz), fu = floorf(pu);
  float wx = px - fx, wy = py - fy, wz = pz - fz, wu = pu - fu;
  unsigned cx = (unsigned)fx, cy = (unsigned)fy, cz = (unsigned)fz, cu = (unsigned)fu;
  unsigned hx[2] = {cx, cx + 1u};
  unsigned hy[2] = {cy * P1, cy * P1 + P1};
  unsigned hz[2] = {cz * P2, cz * P2 + P2};
  unsigned hu[2] = {cu * P3, cu * P3 + P3};
  float vx[2] = {1.f - wx, wx}, vy[2] = {1.f - wy, wy}, vz[2] = {1.f - wz, wz}, vu[2] = {1.f - wu, wu};
  f0 = 0.f; f1 = 0.f;
#pragma unroll
  for (int j = 0; j < 16; ++j) {
    const int dx = (j >> 3) & 1, dy = (j >> 2) & 1, dz = (j >> 1) & 1, du = j & 1;
    unsigned h = (hx[dx] ^ hy[dy] ^ hz[dz] ^ hu[du]) & TMASK;
    float2 g = tab[h];
    float w = ((vx[dx] * vy[dy]) * vz[dz]) * vu[du];
    f0 = fmaf(w, g.x, f0); f1 = fmaf(w, g.y, f1);
  }
}

__global__ __launch_bounds__(256, 2)
void hashgrid_mlp_fused(const float* __restrict__ pos, const float* __restrict__ nrm,
                        const float* __restrict__ pose, const float2* __restrict__ tpos,
                        const float2* __restrict__ tnrm, const float2* __restrict__ tpose,
                        const float* __restrict__ W1, const float* __restrict__ W2,
                        const float* __restrict__ W3, float* __restrict__ out, int n) {
  __shared__ float sW1[96 * WIDTH];
  __shared__ float sW2[WIDTH * WIDTH];
  __shared__ float sW3[WIDTH * 9];
  for (int i = threadIdx.x; i < 96 * WIDTH; i += 256) sW1[i] = W1[i];
  for (int i = threadIdx.x; i < WIDTH * WIDTH; i += 256) sW2[i] = W2[i];
  for (int i = threadIdx.x; i < WIDTH * 9; i += 256) sW3[i] = W3[i];
  __syncthreads();
  const int stride = gridDim.x * 256;
  for (int i = blockIdx.x * 256 + threadIdx.x; i < n; i += stride) {
    float h1[WIDTH];
#pragma unroll
    for (int k = 0; k < WIDTH; ++k) h1[k] = 0.f;
    {
      const float x = pos[3 * i], y = pos[3 * i + 1], z = pos[3 * i + 2];
#pragma unroll
      for (int l = 0; l < NLEV; ++l) {
        float f0, f1;
        enc3_level(tpos + (size_t)l * TSIZE, kResC[l], x, y, z, f0, f1);
        const float* w = &sW1[(2 * l) * WIDTH];
#pragma unroll
        for (int k = 0; k < WIDTH; ++k) h1[k] = fmaf(f1, w[WIDTH + k], fmaf(f0, w[k], h1[k]));
      }
    }
    {
      const float x = nrm[3 * i], y = nrm[3 * i + 1], z = nrm[3 * i + 2];
#pragma unroll
      for (int l = 0; l < NLEV; ++l) {
        float f0, f1;
        enc3_level(tnrm + (size_t)l * TSIZE, kResC[l], x, y, z, f0, f1);
        const float* w = &sW1[(32 + 2 * l) * WIDTH];
#pragma unroll
        for (int k = 0; k < WIDTH; ++k) h1[k] = fmaf(f1, w[WIDTH + k], fmaf(f0, w[k], h1[k]));
      }
    }
    {
      const float x = pose[4 * i], y = pose[4 * i + 1], z = pose[4 * i + 2], u = pose[4 * i + 3];
#pragma unroll
      for (int l = 0; l < NLEV; ++l) {
        float f0, f1;
        enc4_level(tpose + (size_t)l * TSIZE, kResC[l], x, y, z, u, f0, f1);
        const float* w = &sW1[(64 + 2 * l) * WIDTH];
#pragma unroll
        for (int k = 0; k < WIDTH; ++k) h1[k] = fmaf(f1, w[WIDTH + k], fmaf(f0, w[k], h1[k]));
      }
    }
    float h2[WIDTH];
#pragma unroll
    for (int k = 0; k < WIDTH; ++k) h2[k] = 0.f;
#pragma unroll
    for (int j = 0; j < WIDTH; ++j) {
      const float a = fmaxf(h1[j], 0.f);
      const float* w = &sW2[j * WIDTH];
#pragma unroll
      for (int k = 0; k < WIDTH; ++k) h2[k] = fmaf(a, w[k], h2[k]);
    }
    float o[9];
#pragma unroll
    for (int k = 0; k < 9; ++k) o[k] = 0.f;
#pragma unroll
    for (int j = 0; j < WIDTH; ++j) {
      const float a = fmaxf(h2[j], 0.f);
      const float* w = &sW3[j * 9];
#pragma unroll
      for (int k = 0; k < 9; ++k) o[k] = fmaf(a, w[k], o[k]);
    }
#pragma unroll
    for (int k = 0; k < 9; ++k) out[(size_t)i * 9 + k] = o[k];
  }
}

// ============================================================================
extern "C" void kernel_launch(void* const* d_in, const int* in_sizes, int n_in,
                              void* d_out, int out_size, void* d_ws, size_t ws_size,
                              hipStream_t stream) {
  const float* pos  = (const float*)d_in[0];
  const float* nrm  = (const float*)d_in[1];
  const float* pose = (const float*)d_in[2];
  const float2* tpos  = (const float2*)d_in[3];
  const float2* tnrm  = (const float2*)d_in[4];
  const float2* tpose = (const float2*)d_in[5];
  const float* W1 = (const float*)d_in[6];
  const float* W2 = (const float*)d_in[7];
  const float* W3 = (const float*)d_in[8];
  float* out = (float*)d_out;
  const int n = in_sizes[0] / 3;

  const size_t needF = (size_t)96 * n * sizeof(float);
  const size_t needH = (size_t)96 * n * sizeof(__half);
  const int BPP = (n + 255) / 256;          // blocks per (table,level) pass
  const dim3 encGrid(16 * BPP), blk(256), mlpGrid(BPP);

  if (ws_size >= needF) {
    float* enc = (float*)d_ws;
    hipLaunchKernelGGL(encode3<float>, encGrid, blk, 0, stream, pos,  tpos,  enc, n, BPP, 0);
    hipLaunchKernelGGL(encode3<float>, encGrid, blk, 0, stream, nrm,  tnrm,  enc, n, BPP, 32);
    hipLaunchKernelGGL(encode4<float>, encGrid, blk, 0, stream, pose, tpose, enc, n, BPP, 64);
    hipLaunchKernelGGL(mlp_pass<float>, mlpGrid, blk, 0, stream, enc, W1, W2, W3, out, n);
  } else if (ws_size >= needH) {
    __half* enc = (__half*)d_ws;
    hipLaunchKernelGGL(encode3<__half>, encGrid, blk, 0, stream, pos,  tpos,  enc, n, BPP, 0);
    hipLaunchKernelGGL(encode3<__half>, encGrid, blk, 0, stream, nrm,  tnrm,  enc, n, BPP, 32);
    hipLaunchKernelGGL(encode4<__half>, encGrid, blk, 0, stream, pose, tpose, enc, n, BPP, 64);
    hipLaunchKernelGGL(mlp_pass<__half>, mlpGrid, blk, 0, stream, enc, W1, W2, W3, out, n);
  } else {
    hipLaunchKernelGGL(hashgrid_mlp_fused, dim3(512), blk, 0, stream,
                       pos, nrm, pose, tpos, tnrm, tpose, W1, W2, W3, out, n);
  }
}

// Round 6
// 2050.730 us; speedup vs baseline: 2.6011x; 1.3304x over previous
//
#include <hip/hip_runtime.h>
#include <hip/hip_fp16.h>

#define NLEV 16
#define TSIZE (1u << 19)
#define TMASK (TSIZE - 1u)
#define WIDTH 64
#define P1 2654435761u
#define P2 805459861u
#define P3 3674653429u

// floor(16 * 1.5^l) — exactly representable in f32
__constant__ float kResC[NLEV] = {16.f, 24.f, 36.f, 54.f, 81.f, 121.f, 182.f, 273.f,
                                  410.f, 615.f, 922.f, 1383.f, 2075.f, 3113.f, 4670.f, 7006.f};

// 16B gather usable at 8B alignment (hardware needs only dword alignment)
struct __attribute__((packed, aligned(8))) pf4 { float x, y, z, w; };

// ---- non-temporal helpers (streaming data shouldn't evict the table slice)
__device__ __forceinline__ void st_nt(float* p, float v) { __builtin_nontemporal_store(v, p); }
__device__ __forceinline__ void st_nt(__half* p, float v) {
  __builtin_nontemporal_store(__half_as_ushort(__float2half(v)), (unsigned short*)p);
}
__device__ __forceinline__ float ld_nt_f(const float* p) { return __builtin_nontemporal_load(p); }
__device__ __forceinline__ float ld_enc(const float* p) { return __builtin_nontemporal_load(p); }
__device__ __forceinline__ float ld_enc(const __half* p) {
  return __half2float(__ushort_as_half(__builtin_nontemporal_load((const unsigned short*)p)));
}

// ============================================================================
// Encode: one (table, level) 4 MB slice per pass (L2-resident per XCD).
// Gather-count optimization: x-dim prime is 1, so the two x-corners of a cell
// hash to indices i0, i0^(2^(k+1)-1) — numerically adjacent ~66% of the time.
// Adjacent pair -> ONE dwordx4 gather; else dwordx4 + exec-masked dwordx2.
// Avg lane-gathers per pair: 1.34 vs 2.0 (-33%). lo<=TMASK-1 always (lo<hi).
// ============================================================================

template <typename ST>
__global__ __launch_bounds__(256)
void encode3(const float* __restrict__ coords,   // [N,3]
             const float2* __restrict__ table,   // [16][TSIZE] float2
             ST* __restrict__ enc,               // [96][N]
             int N, int BPP, int rowBase) {
  const unsigned blk = blockIdx.x;
  const unsigned lvl = blk / (unsigned)BPP;
  const unsigned b = blk - lvl * (unsigned)BPP;
  const int i = (int)(b * 256u + threadIdx.x);
  if (i >= N) return;
  const float res = kResC[lvl];
  const float2* __restrict__ tab = table + (size_t)lvl * TSIZE;

  const float px = ld_nt_f(&coords[(size_t)i * 3 + 0]) * res;
  const float py = ld_nt_f(&coords[(size_t)i * 3 + 1]) * res;
  const float pz = ld_nt_f(&coords[(size_t)i * 3 + 2]) * res;
  const float fx = floorf(px), fy = floorf(py), fz = floorf(pz);
  const float wx = px - fx, wy = py - fy, wz = pz - fz;
  const unsigned cx = (unsigned)fx, cy = (unsigned)fy, cz = (unsigned)fz;
  const unsigned hx0 = cx, hx1 = cx + 1u;
  const unsigned hy0 = cy * P1, hy1 = hy0 + P1;
  const unsigned hz0 = cz * P2, hz1 = hz0 + P2;
  const float vx0 = 1.f - wx, vx1 = wx;
  const float vy0 = 1.f - wy, vy1 = wy;
  const float vz0 = 1.f - wz, vz1 = wz;

  const unsigned Yp[4] = {hy0 ^ hz0, hy0 ^ hz1, hy1 ^ hz0, hy1 ^ hz1};
  const float   wp4[4] = {vy0 * vz0, vy0 * vz1, vy1 * vz0, vy1 * vz1};

  float f0 = 0.f, f1 = 0.f;
#pragma unroll
  for (int p = 0; p < 4; ++p) {
    const unsigned i0 = (hx0 ^ Yp[p]) & TMASK;   // x=0 corner
    const unsigned i1 = (hx1 ^ Yp[p]) & TMASK;   // x=1 corner
    const unsigned lo = i0 < i1 ? i0 : i1;
    const unsigned hi = i0 < i1 ? i1 : i0;
    const bool adj = (hi - lo) == 1u;
    const pf4 q = *(const pf4*)(tab + lo);       // entries lo, lo+1 (in-bounds: lo<hi<=TMASK)
    const float2 elo = {q.x, q.y};
    float2 eo = elo;
    if (!adj) eo = tab[hi];                      // exec-masked: only ~34% of lanes gather
    const float ehix = adj ? q.z : eo.x;
    const float ehiy = adj ? q.w : eo.y;
    const bool i0lo = (i0 == lo);
    const float e0x = i0lo ? elo.x : ehix, e0y = i0lo ? elo.y : ehiy;
    const float e1x = i0lo ? ehix : elo.x, e1y = i0lo ? ehiy : elo.y;
    const float w0 = wp4[p] * vx0, w1 = wp4[p] * vx1;
    f0 = fmaf(w0, e0x, fmaf(w1, e1x, f0));
    f1 = fmaf(w0, e0y, fmaf(w1, e1y, f1));
  }
  const int row = rowBase + 2 * (int)lvl;
  st_nt(&enc[(size_t)row * N + i], f0);
  st_nt(&enc[(size_t)(row + 1) * N + i], f1);
}

template <typename ST>
__global__ __launch_bounds__(256)
void encode4(const float* __restrict__ coords,   // [N,4]
             const float2* __restrict__ table,
             ST* __restrict__ enc,
             int N, int BPP, int rowBase) {
  const unsigned blk = blockIdx.x;
  const unsigned lvl = blk / (unsigned)BPP;
  const unsigned b = blk - lvl * (unsigned)BPP;
  const int i = (int)(b * 256u + threadIdx.x);
  if (i >= N) return;
  const float res = kResC[lvl];
  const float2* __restrict__ tab = table + (size_t)lvl * TSIZE;

  const float px = ld_nt_f(&coords[(size_t)i * 4 + 0]) * res;
  const float py = ld_nt_f(&coords[(size_t)i * 4 + 1]) * res;
  const float pz = ld_nt_f(&coords[(size_t)i * 4 + 2]) * res;
  const float pu = ld_nt_f(&coords[(size_t)i * 4 + 3]) * res;
  const float fx = floorf(px), fy = floorf(py), fz = floorf(pz), fu = floorf(pu);
  const float wx = px - fx, wy = py - fy, wz = pz - fz, wu = pu - fu;
  const unsigned cx = (unsigned)fx, cy = (unsigned)fy, cz = (unsigned)fz, cu = (unsigned)fu;
  const unsigned hx0 = cx, hx1 = cx + 1u;
  const unsigned hy0 = cy * P1, hy1 = hy0 + P1;
  const unsigned hz0 = cz * P2, hz1 = hz0 + P2;
  const unsigned hu0 = cu * P3, hu1 = hu0 + P3;
  const float vx0 = 1.f - wx, vx1 = wx;
  const float vy0 = 1.f - wy, vy1 = wy;
  const float vz0 = 1.f - wz, vz1 = wz;
  const float vu0 = 1.f - wu, vu1 = wu;

  unsigned Yp[8];
  float wp8[8];
#pragma unroll
  for (int p = 0; p < 8; ++p) {
    const unsigned hy = (p & 4) ? hy1 : hy0;
    const unsigned hz = (p & 2) ? hz1 : hz0;
    const unsigned hu = (p & 1) ? hu1 : hu0;
    Yp[p] = hy ^ hz ^ hu;
    wp8[p] = ((p & 4) ? vy1 : vy0) * ((p & 2) ? vz1 : vz0) * ((p & 1) ? vu1 : vu0);
  }

  float f0 = 0.f, f1 = 0.f;
#pragma unroll
  for (int p = 0; p < 8; ++p) {
    const unsigned i0 = (hx0 ^ Yp[p]) & TMASK;
    const unsigned i1 = (hx1 ^ Yp[p]) & TMASK;
    const unsigned lo = i0 < i1 ? i0 : i1;
    const unsigned hi = i0 < i1 ? i1 : i0;
    const bool adj = (hi - lo) == 1u;
    const pf4 q = *(const pf4*)(tab + lo);
    const float2 elo = {q.x, q.y};
    float2 eo = elo;
    if (!adj) eo = tab[hi];
    const float ehix = adj ? q.z : eo.x;
    const float ehiy = adj ? q.w : eo.y;
    const bool i0lo = (i0 == lo);
    const float e0x = i0lo ? elo.x : ehix, e0y = i0lo ? elo.y : ehiy;
    const float e1x = i0lo ? ehix : elo.x, e1y = i0lo ? ehiy : elo.y;
    const float w0 = wp8[p] * vx0, w1 = wp8[p] * vx1;
    f0 = fmaf(w0, e0x, fmaf(w1, e1x, f0));
    f1 = fmaf(w0, e0y, fmaf(w1, e1y, f1));
  }
  const int row = rowBase + 2 * (int)lvl;
  st_nt(&enc[(size_t)row * N + i], f0);
  st_nt(&enc[(size_t)(row + 1) * N + i], f1);
}

// ============================================================================
// MLP pass: enc[96][N] -> out[N][9]. Weights read DIRECTLY from global with
// wave-uniform indices -> compiler scalarizes to s_load + v_fmac (SGPR src),
// removing the per-FMA LDS issue slot of the previous version.
// ============================================================================
template <typename ST>
__global__ __launch_bounds__(256)
void mlp_pass(const ST* __restrict__ enc,
              const float* __restrict__ W1, const float* __restrict__ W2,
              const float* __restrict__ W3, float* __restrict__ out, int N) {
  const int i = blockIdx.x * 256 + threadIdx.x;
  if (i >= N) return;

  float h1[WIDTH];
#pragma unroll
  for (int j = 0; j < WIDTH; ++j) h1[j] = 0.f;
#pragma unroll 1
  for (int kb = 0; kb < 96; kb += 8) {
    float a8[8];
#pragma unroll
    for (int t = 0; t < 8; ++t) a8[t] = ld_enc(&enc[(size_t)(kb + t) * N + i]);
#pragma unroll
    for (int t = 0; t < 8; ++t) {
      const float* w = &W1[(kb + t) * WIDTH];   // uniform address -> s_load
#pragma unroll
      for (int j = 0; j < WIDTH; ++j) h1[j] = fmaf(a8[t], w[j], h1[j]);
    }
  }

  float h2[WIDTH];
#pragma unroll
  for (int j = 0; j < WIDTH; ++j) h2[j] = 0.f;
#pragma unroll
  for (int j = 0; j < WIDTH; ++j) {   // full unroll: h1/h2 stay reg-indexed
    const float a = fmaxf(h1[j], 0.f);
    const float* w = &W2[j * WIDTH];
#pragma unroll
    for (int k = 0; k < WIDTH; ++k) h2[k] = fmaf(a, w[k], h2[k]);
  }

  float o[9];
#pragma unroll
  for (int k = 0; k < 9; ++k) o[k] = 0.f;
#pragma unroll
  for (int j = 0; j < WIDTH; ++j) {
    const float a = fmaxf(h2[j], 0.f);
    const float* w = &W3[j * 9];
#pragma unroll
    for (int k = 0; k < 9; ++k) o[k] = fmaf(a, w[k], o[k]);
  }
#pragma unroll
  for (int k = 0; k < 9; ++k) st_nt(&out[(size_t)i * 9 + k], o[k]);
}

// ============================================================================
// Fallback: fused kernel (known-correct) if workspace is too small.
// ============================================================================
__device__ __forceinline__ void enc3_level(const float2* __restrict__ tab, float res,
                                           float x, float y, float z, float& f0, float& f1) {
  float px = x * res, py = y * res, pz = z * res;
  float fx = floorf(px), fy = floorf(py), fz = floorf(pz);
  float wx = px - fx, wy = py - fy, wz = pz - fz;
  unsigned cx = (unsigned)fx, cy = (unsigned)fy, cz = (unsigned)fz;
  unsigned hx[2] = {cx, cx + 1u};
  unsigned hy[2] = {cy * P1, cy * P1 + P1};
  unsigned hz[2] = {cz * P2, cz * P2 + P2};
  float vx[2] = {1.f - wx, wx}, vy[2] = {1.f - wy, wy}, vz[2] = {1.f - wz, wz};
  f0 = 0.f; f1 = 0.f;
#pragma unroll
  for (int j = 0; j < 8; ++j) {
    const int dx = (j >> 2) & 1, dy = (j >> 1) & 1, dz = j & 1;
    unsigned h = (hx[dx] ^ hy[dy] ^ hz[dz]) & TMASK;
    float2 g = tab[h];
    float w = vx[dx] * vy[dy] * vz[dz];
    f0 = fmaf(w, g.x, f0); f1 = fmaf(w, g.y, f1);
  }
}
__device__ __forceinline__ void enc4_level(const float2* __restrict__ tab, float res,
                                           float x, float y, float z, float u, float& f0, float& f1) {
  float px = x * res, py = y * res, pz = z * res, pu = u * res;
  float fx = floorf(px), fy = floorf(py), fz = floorf(pz), fu = floorf(pu);
  float wx = px - fx, wy = py - fy, wz = pz - fz, wu = pu - fu;
  unsigned cx = (unsigned)fx, cy = (unsigned)fy, cz = (unsigned)fz, cu = (unsigned)fu;
  unsigned hx[2] = {cx, cx + 1u};
  unsigned hy[2] = {cy * P1, cy * P1 + P1};
  unsigned hz[2] = {cz * P2, cz * P2 + P2};
  unsigned hu[2] = {cu * P3, cu * P3 + P3};
  float vx[2] = {1.f - wx, wx}, vy[2] = {1.f - wy, wy}, vz[2] = {1.f - wz, wz}, vu[2] = {1.f - wu, wu};
  f0 = 0.f; f1 = 0.f;
#pragma unroll
  for (int j = 0; j < 16; ++j) {
    const int dx = (j >> 3) & 1, dy = (j >> 2) & 1, dz = (j >> 1) & 1, du = j & 1;
    unsigned h = (hx[dx] ^ hy[dy] ^ hz[dz] ^ hu[du]) & TMASK;
    float2 g = tab[h];
    float w = ((vx[dx] * vy[dy]) * vz[dz]) * vu[du];
    f0 = fmaf(w, g.x, f0); f1 = fmaf(w, g.y, f1);
  }
}

__global__ __launch_bounds__(256, 2)
void hashgrid_mlp_fused(const float* __restrict__ pos, const float* __restrict__ nrm,
                        const float* __restrict__ pose, const float2* __restrict__ tpos,
                        const float2* __restrict__ tnrm, const float2* __restrict__ tpose,
                        const float* __restrict__ W1, const float* __restrict__ W2,
                        const float* __restrict__ W3, float* __restrict__ out, int n) {
  __shared__ float sW1[96 * WIDTH];
  __shared__ float sW2[WIDTH * WIDTH];
  __shared__ float sW3[WIDTH * 9];
  for (int i = threadIdx.x; i < 96 * WIDTH; i += 256) sW1[i] = W1[i];
  for (int i = threadIdx.x; i < WIDTH * WIDTH; i += 256) sW2[i] = W2[i];
  for (int i = threadIdx.x; i < WIDTH * 9; i += 256) sW3[i] = W3[i];
  __syncthreads();
  const int stride = gridDim.x * 256;
  for (int i = blockIdx.x * 256 + threadIdx.x; i < n; i += stride) {
    float h1[WIDTH];
#pragma unroll
    for (int k = 0; k < WIDTH; ++k) h1[k] = 0.f;
    {
      const float x = pos[3 * i], y = pos[3 * i + 1], z = pos[3 * i + 2];
#pragma unroll
      for (int l = 0; l < NLEV; ++l) {
        float f0, f1;
        enc3_level(tpos + (size_t)l * TSIZE, kResC[l], x, y, z, f0, f1);
        const float* w = &sW1[(2 * l) * WIDTH];
#pragma unroll
        for (int k = 0; k < WIDTH; ++k) h1[k] = fmaf(f1, w[WIDTH + k], fmaf(f0, w[k], h1[k]));
      }
    }
    {
      const float x = nrm[3 * i], y = nrm[3 * i + 1], z = nrm[3 * i + 2];
#pragma unroll
      for (int l = 0; l < NLEV; ++l) {
        float f0, f1;
        enc3_level(tnrm + (size_t)l * TSIZE, kResC[l], x, y, z, f0, f1);
        const float* w = &sW1[(32 + 2 * l) * WIDTH];
#pragma unroll
        for (int k = 0; k < WIDTH; ++k) h1[k] = fmaf(f1, w[WIDTH + k], fmaf(f0, w[k], h1[k]));
      }
    }
    {
      const float x = pose[4 * i], y = pose[4 * i + 1], z = pose[4 * i + 2], u = pose[4 * i + 3];
#pragma unroll
      for (int l = 0; l < NLEV; ++l) {
        float f0, f1;
        enc4_level(tpose + (size_t)l * TSIZE, kResC[l], x, y, z, u, f0, f1);
        const float* w = &sW1[(64 + 2 * l) * WIDTH];
#pragma unroll
        for (int k = 0; k < WIDTH; ++k) h1[k] = fmaf(f1, w[WIDTH + k], fmaf(f0, w[k], h1[k]));
      }
    }
    float h2[WIDTH];
#pragma unroll
    for (int k = 0; k < WIDTH; ++k) h2[k] = 0.f;
#pragma unroll
    for (int j = 0; j < WIDTH; ++j) {
      const float a = fmaxf(h1[j], 0.f);
      const float* w = &sW2[j * WIDTH];
#pragma unroll
      for (int k = 0; k < WIDTH; ++k) h2[k] = fmaf(a, w[k], h2[k]);
    }
    float o[9];
#pragma unroll
    for (int k = 0; k < 9; ++k) o[k] = 0.f;
#pragma unroll
    for (int j = 0; j < WIDTH; ++j) {
      const float a = fmaxf(h2[j], 0.f);
      const float* w = &sW3[j * 9];
#pragma unroll
      for (int k = 0; k < 9; ++k) o[k] = fmaf(a, w[k], o[k]);
    }
#pragma unroll
    for (int k = 0; k < 9; ++k) out[(size_t)i * 9 + k] = o[k];
  }
}

// ============================================================================
extern "C" void kernel_launch(void* const* d_in, const int* in_sizes, int n_in,
                              void* d_out, int out_size, void* d_ws, size_t ws_size,
                              hipStream_t stream) {
  const float* pos  = (const float*)d_in[0];
  const float* nrm  = (const float*)d_in[1];
  const float* pose = (const float*)d_in[2];
  const float2* tpos  = (const float2*)d_in[3];
  const float2* tnrm  = (const float2*)d_in[4];
  const float2* tpose = (const float2*)d_in[5];
  const float* W1 = (const float*)d_in[6];
  const float* W2 = (const float*)d_in[7];
  const float* W3 = (const float*)d_in[8];
  float* out = (float*)d_out;
  const int n = in_sizes[0] / 3;

  const size_t needF = (size_t)96 * n * sizeof(float);
  const size_t needH = (size_t)96 * n * sizeof(__half);
  const int BPP = (n + 255) / 256;          // blocks per (table,level) pass
  const dim3 encGrid(16 * BPP), blk(256), mlpGrid(BPP);

  if (ws_size >= needF) {
    float* enc = (float*)d_ws;
    hipLaunchKernelGGL(encode3<float>, encGrid, blk, 0, stream, pos,  tpos,  enc, n, BPP, 0);
    hipLaunchKernelGGL(encode3<float>, encGrid, blk, 0, stream, nrm,  tnrm,  enc, n, BPP, 32);
    hipLaunchKernelGGL(encode4<float>, encGrid, blk, 0, stream, pose, tpose, enc, n, BPP, 64);
    hipLaunchKernelGGL(mlp_pass<float>, mlpGrid, blk, 0, stream, enc, W1, W2, W3, out, n);
  } else if (ws_size >= needH) {
    __half* enc = (__half*)d_ws;
    hipLaunchKernelGGL(encode3<__half>, encGrid, blk, 0, stream, pos,  tpos,  enc, n, BPP, 0);
    hipLaunchKernelGGL(encode3<__half>, encGrid, blk, 0, stream, nrm,  tnrm,  enc, n, BPP, 32);
    hipLaunchKernelGGL(encode4<__half>, encGrid, blk, 0, stream, pose, tpose, enc, n, BPP, 64);
    hipLaunchKernelGGL(mlp_pass<__half>, mlpGrid, blk, 0, stream, enc, W1, W2, W3, out, n);
  } else {
    hipLaunchKernelGGL(hashgrid_mlp_fused, dim3(512), blk, 0, stream,
                       pos, nrm, pose, tpos, tnrm, tpose, W1, W2, W3, out, n);
  }
}